// Round 6
// baseline (136.546 us; speedup 1.0000x reference)
//
#include <hip/hip_runtime.h>

#define EPS 1e-5f

typedef __attribute__((ext_vector_type(4))) float f32x4;
typedef __attribute__((ext_vector_type(8))) _Float16 f16x8;
typedef __attribute__((ext_vector_type(4))) _Float16 f16x4;

// ============ kernel 1: prep ∥ convxT/xh ∥ am->fp16 ============
// blocks [0,256): x -> XT (transposed fp16) + xh (row-major fp16)
// blocks [256,320): BN-fold weights, biases, offsets, task table (16-row tiles)
// blocks [320,832): am fp32 -> amh fp16 (only rows/cols < l per graph)
__global__ __launch_bounds__(256) void prep_conv_kernel(
    const int* __restrict__ ld, const float* __restrict__ am,
    const float* __restrict__ Wl, const float* __restrict__ bl,
    const float* __restrict__ gl, const float* __restrict__ betal,
    const float* __restrict__ ml, const float* __restrict__ vl,
    const float* __restrict__ W1, const float* __restrict__ b1,
    const float* __restrict__ g1, const float* __restrict__ beta1,
    const float* __restrict__ m1, const float* __restrict__ v1,
    const float* __restrict__ W2, const float* __restrict__ b2,
    const float* __restrict__ g2, const float* __restrict__ beta2,
    const float* __restrict__ m2, const float* __restrict__ v2,
    int* __restrict__ offs, float* __restrict__ c1, float* __restrict__ cf,
    int* __restrict__ tg, int* __restrict__ tr, int n_tasks,
    _Float16* __restrict__ W1h, _Float16* __restrict__ Wch,
    _Float16* __restrict__ amh,
    const float* __restrict__ x, _Float16* __restrict__ XT,
    _Float16* __restrict__ xh, int M)
{
    __shared__ __align__(16) _Float16 Tt[128][80];
    int t = threadIdx.x;
    if (blockIdx.x < 256) {
        int m0 = blockIdx.x * 64;
        #pragma unroll
        for (int p = 0; p < 8; ++p) {
            int idx = t + p * 256;
            int m = idx >> 5;
            int f = (idx & 31) * 4;
            float4 v = *(const float4*)&x[(size_t)(m0 + m) * 128 + f];
            Tt[f + 0][m] = (_Float16)v.x; Tt[f + 1][m] = (_Float16)v.y;
            Tt[f + 2][m] = (_Float16)v.z; Tt[f + 3][m] = (_Float16)v.w;
            f16x4 h;
            h[0] = (_Float16)v.x; h[1] = (_Float16)v.y;
            h[2] = (_Float16)v.z; h[3] = (_Float16)v.w;
            *(f16x4*)&xh[(size_t)(m0 + m) * 128 + f] = h;
        }
        __syncthreads();
        #pragma unroll
        for (int p = 0; p < 4; ++p) {
            int idx = t + p * 256;
            int f = idx >> 3;
            int m8 = (idx & 7) * 8;
            uint4 v = *(const uint4*)&Tt[f][m8];
            *(uint4*)&XT[(size_t)f * M + m0 + m8] = v;
        }
    } else if (blockIdx.x < 320) {
        int b = blockIdx.x - 256;
        int gt = b * 256 + t;
        const int gsize = 64 * 256;
        if (b == 0) {
            if (t < 64) {
                int s = 0;
                for (int i = 0; i < t; ++i) s += ld[i];
                offs[t] = s;
            }
            if (t < 128) {
                float s1 = g1[t] * rsqrtf(v1[t] + EPS);
                c1[t] = (b1[t] - m1[t]) * s1 + beta1[t];
            }
            if (t < 256) {
                float s2 = g2[t] * rsqrtf(v2[t] + EPS);
                float sl = gl[t] * rsqrtf(vl[t] + EPS);
                cf[t] = (b2[t] - m2[t]) * s2 + beta2[t] + (bl[t] - ml[t]) * sl + betal[t];
            }
            // task table: 16-row tiles over the ragged rows
            for (int t2 = t; t2 < n_tasks; t2 += 256) {
                int rem = t2, gg = 0;
                while (true) {
                    int n = ld[gg] >> 4;
                    if (rem < n) break;
                    rem -= n; ++gg;
                }
                tg[t2] = gg;
                tr[t2] = rem << 4;
            }
        }
        for (int idx = gt; idx < 128 * 128; idx += gsize) {
            int n = idx >> 7;
            float s1 = g1[n] * rsqrtf(v1[n] + EPS);
            W1h[idx] = (_Float16)(W1[idx] * s1);
        }
        for (int idx = gt; idx < 256 * 256; idx += gsize) {
            int n = idx >> 8, k = idx & 255;
            float v;
            if (k < 128) {
                float s2 = g2[n] * rsqrtf(v2[n] + EPS);
                v = W2[n * 128 + k] * s2;
            } else {
                float sl = gl[n] * rsqrtf(vl[n] + EPS);
                v = Wl[n * 128 + (k - 128)] * sl;
            }
            Wch[idx] = (_Float16)v;
        }
    } else {
        // am -> fp16, 32-row tile per block (512 blocks)
        int t2 = blockIdx.x - 320;
        int rem = t2, gg = 0;
        while (true) {
            int n = ld[gg] >> 5;
            if (rem < n) break;
            rem -= n; ++gg;
        }
        int r0 = rem << 5;
        int l = ld[gg];
        const float* src = am + (size_t)gg * (512 * 512);
        _Float16* dst = amh + (size_t)gg * (512 * 512);
        int lq = l >> 2;                 // quads per row
        int tot = lq << 5;               // 32 rows
        for (int q = t; q < tot; q += 256) {
            int row = q / lq;
            int c4 = (q - row * lq) << 2;
            size_t o = (size_t)(r0 + row) * 512 + c4;
            float4 v = *(const float4*)&src[o];
            f16x4 h;
            h[0] = (_Float16)v.x; h[1] = (_Float16)v.y;
            h[2] = (_Float16)v.z; h[3] = (_Float16)v.w;
            *(f16x4*)&dst[o] = h;
        }
    }
}

__device__ __forceinline__ void agg_phaseA(
    const _Float16* __restrict__ src, const _Float16* __restrict__ arow,
    int fb, int l15, int l4, size_t Msz, int off, int nk,
    f32x4& acc0, f32x4& acc1)
{
    const _Float16* s0 = src + (size_t)(fb + l15) * Msz + off + l4 * 8;
    const _Float16* s1 = src + (size_t)(fb + 16 + l15) * Msz + off + l4 * 8;

    uint4 pa0[2], pa1[2], pb[2];
    pa0[0] = *(const uint4*)(s0);
    pa1[0] = *(const uint4*)(s1);
    pb[0]  = *(const uint4*)(arow);
    pa0[1] = *(const uint4*)(s0 + 32);
    pa1[1] = *(const uint4*)(s1 + 32);
    pb[1]  = *(const uint4*)(arow + 32);

    #pragma unroll 4
    for (int s = 0; s < nk; ++s) {
        int sl = s & 1;
        f16x8 a0 = *(f16x8*)&pa0[sl];
        f16x8 a1 = *(f16x8*)&pa1[sl];
        f16x8 b  = *(f16x8*)&pb[sl];
        if (s + 2 < nk) {
            int k0 = (s + 2) * 32;
            pa0[sl] = *(const uint4*)(s0 + k0);
            pa1[sl] = *(const uint4*)(s1 + k0);
            pb[sl]  = *(const uint4*)(arow + k0);
        }
        acc0 = __builtin_amdgcn_mfma_f32_16x16x32_f16(a0, b, acc0, 0, 0, 0);
        acc1 = __builtin_amdgcn_mfma_f32_16x16x32_f16(a1, b, acc1, 0, 0, 0);
    }
}

// ============ kernel 2: fused agg1 + lin1 -> h2T (16-row tasks, 4 waves) ============
__global__ __launch_bounds__(256) void fused1w_kernel(
    const _Float16* __restrict__ amh, const _Float16* __restrict__ XT,
    const int* __restrict__ ld, const int* __restrict__ offs,
    const int* __restrict__ tg, const int* __restrict__ tr,
    const _Float16* __restrict__ Wh, const float* __restrict__ bias,
    _Float16* __restrict__ outT, int M)
{
    int task = blockIdx.x;
    int g = tg[task];
    int l = ld[g];
    int off = offs[g];
    int r0 = tr[task];

    int tid = threadIdx.x;
    int lane = tid & 63;
    int w = tid >> 6;
    int l15 = lane & 15;
    int l4 = lane >> 4;
    int fb = w * 32;

    __shared__ __align__(16) _Float16 Hs[16][136];

    const _Float16* arow = amh + (size_t)g * (512 * 512) + (size_t)(r0 + l15) * 512 + l4 * 8;

    f32x4 acc0 = {0.f, 0.f, 0.f, 0.f}, acc1 = {0.f, 0.f, 0.f, 0.f};
    agg_phaseA(XT, arow, fb, l15, l4, (size_t)M, off, l >> 5, acc0, acc1);

    f16x4 o0, o1;
    #pragma unroll
    for (int r = 0; r < 4; ++r) { o0[r] = (_Float16)acc0[r]; o1[r] = (_Float16)acc1[r]; }
    *(f16x4*)&Hs[l15][fb + l4 * 4] = o0;
    *(f16x4*)&Hs[l15][fb + 16 + l4 * 4] = o1;
    __syncthreads();

    // phase B: K=128, this wave computes out-feats [nb, nb+32)
    int nb = w * 32;
    f32x4 c0 = {0.f, 0.f, 0.f, 0.f}, c1v = {0.f, 0.f, 0.f, 0.f};
    #pragma unroll
    for (int s = 0; s < 4; ++s) {
        int k0 = s * 32;
        f16x8 a  = *(const f16x8*)&Hs[l15][k0 + l4 * 8];
        f16x8 b0 = *(const f16x8*)&Wh[(size_t)(nb + l15) * 128 + k0 + l4 * 8];
        f16x8 b1 = *(const f16x8*)&Wh[(size_t)(nb + 16 + l15) * 128 + k0 + l4 * 8];
        c0  = __builtin_amdgcn_mfma_f32_16x16x32_f16(a, b0, c0, 0, 0, 0);
        c1v = __builtin_amdgcn_mfma_f32_16x16x32_f16(a, b1, c1v, 0, 0, 0);
    }
    int gm0 = off + r0;
    #pragma unroll
    for (int j = 0; j < 2; ++j) {
        int n = nb + j * 16 + l15;
        float bv = bias[n];
        f32x4 c = j ? c1v : c0;
        f16x4 o;
        #pragma unroll
        for (int r = 0; r < 4; ++r) {
            float v = c[r] + bv;
            o[r] = (_Float16)(v > 0.f ? v : 0.f);
        }
        *(f16x4*)&outT[(size_t)n * M + gm0 + l4 * 4] = o;
    }
}

// ============ kernel 3: fused agg2 + final -> out fp32 (16-row tasks, 4 waves) ============
__global__ __launch_bounds__(256) void fused2w_kernel(
    const _Float16* __restrict__ amh, const _Float16* __restrict__ H2T,
    const int* __restrict__ ld, const int* __restrict__ offs,
    const int* __restrict__ tg, const int* __restrict__ tr,
    const _Float16* __restrict__ xh, const _Float16* __restrict__ Wch,
    const float* __restrict__ bias, float* __restrict__ out, int M)
{
    int task = blockIdx.x;
    int g = tg[task];
    int l = ld[g];
    int off = offs[g];
    int r0 = tr[task];

    int tid = threadIdx.x;
    int lane = tid & 63;
    int w = tid >> 6;
    int l15 = lane & 15;
    int l4 = lane >> 4;
    int fb = w * 32;

    __shared__ __align__(16) _Float16 Hs[16][136];

    const _Float16* arow = amh + (size_t)g * (512 * 512) + (size_t)(r0 + l15) * 512 + l4 * 8;

    f32x4 acc0 = {0.f, 0.f, 0.f, 0.f}, acc1 = {0.f, 0.f, 0.f, 0.f};
    agg_phaseA(H2T, arow, fb, l15, l4, (size_t)M, off, l >> 5, acc0, acc1);

    f16x4 o0, o1;
    #pragma unroll
    for (int r = 0; r < 4; ++r) { o0[r] = (_Float16)acc0[r]; o1[r] = (_Float16)acc1[r]; }
    *(f16x4*)&Hs[l15][fb + l4 * 4] = o0;
    *(f16x4*)&Hs[l15][fb + 16 + l4 * 4] = o1;
    __syncthreads();

    // phase B: K=256 ([h3 | x]), this wave computes out-feats [nb, nb+64)
    int gm0 = off + r0;
    int nb = w * 64;
    f32x4 c[4];
    #pragma unroll
    for (int j = 0; j < 4; ++j) c[j] = (f32x4){0.f, 0.f, 0.f, 0.f};
    #pragma unroll
    for (int s = 0; s < 8; ++s) {
        int k0 = s * 32;
        f16x8 a;
        if (s < 4)
            a = *(const f16x8*)&Hs[l15][k0 + l4 * 8];
        else
            a = *(const f16x8*)&xh[(size_t)(gm0 + l15) * 128 + (k0 - 128) + l4 * 8];
        #pragma unroll
        for (int j = 0; j < 4; ++j) {
            f16x8 b = *(const f16x8*)&Wch[(size_t)(nb + j * 16 + l15) * 256 + k0 + l4 * 8];
            c[j] = __builtin_amdgcn_mfma_f32_16x16x32_f16(a, b, c[j], 0, 0, 0);
        }
    }
    #pragma unroll
    for (int j = 0; j < 4; ++j) {
        int n = nb + j * 16 + l15;
        float bv = bias[n];
        #pragma unroll
        for (int r = 0; r < 4; ++r) {
            int m = gm0 + l4 * 4 + r;
            float v = c[j][r] + bv;
            out[(size_t)m * 256 + n] = v > 0.f ? v : 0.01f * v;
        }
    }
}

extern "C" void kernel_launch(void* const* d_in, const int* in_sizes, int n_in,
                              void* d_out, int out_size, void* d_ws, size_t ws_size,
                              hipStream_t stream) {
    const float* x     = (const float*)d_in[0];
    const int*   ld    = (const int*)d_in[1];
    const float* am    = (const float*)d_in[2];
    const float* Wl    = (const float*)d_in[3];
    const float* bl    = (const float*)d_in[4];
    const float* gl    = (const float*)d_in[5];
    const float* betal = (const float*)d_in[6];
    const float* ml    = (const float*)d_in[7];
    const float* vl    = (const float*)d_in[8];
    const float* W1    = (const float*)d_in[9];
    const float* b1    = (const float*)d_in[10];
    const float* g1    = (const float*)d_in[11];
    const float* beta1 = (const float*)d_in[12];
    const float* m1    = (const float*)d_in[13];
    const float* v1    = (const float*)d_in[14];
    const float* W2    = (const float*)d_in[15];
    const float* b2    = (const float*)d_in[16];
    const float* g2    = (const float*)d_in[17];
    const float* beta2 = (const float*)d_in[18];
    const float* m2    = (const float*)d_in[19];
    const float* v2    = (const float*)d_in[20];
    float* out = (float*)d_out;

    int M = in_sizes[0] / 128;   // 16384
    int n_tasks = M / 16;        // 1024

    char* w = (char*)d_ws;
    int*   offs = (int*)(w);                    // 64 int
    float* c1   = (float*)(w + 512);            // 128 f
    float* cf   = (float*)(w + 1024);           // 256 f
    int*   tg   = (int*)(w + 2048);             // 1024 int
    int*   tr   = (int*)(w + 6144);             // 1024 int
    _Float16* W1h = (_Float16*)(w + 16384);     // 128*128
    _Float16* Wch = (_Float16*)(w + 49152);     // 256*256
    _Float16* amh = (_Float16*)(w + 180224);    // 64*512*512 fp16 = 33.5 MB
    _Float16* XT  = (_Float16*)(w + 180224 + (size_t)64 * 512 * 512 * 2);
    _Float16* xh  = XT + (size_t)M * 128;
    _Float16* h2T = xh + (size_t)M * 128;

    prep_conv_kernel<<<832, 256, 0, stream>>>(ld, am,
        Wl, bl, gl, betal, ml, vl,
        W1, b1, g1, beta1, m1, v1,
        W2, b2, g2, beta2, m2, v2,
        offs, c1, cf, tg, tr, n_tasks, W1h, Wch, amh, x, XT, xh, M);

    fused1w_kernel<<<n_tasks, 256, 0, stream>>>(amh, XT, ld, offs, tg, tr, W1h, c1, h2T, M);

    fused2w_kernel<<<n_tasks, 256, 0, stream>>>(amh, h2T, ld, offs, tg, tr, xh, Wch, cf, out, M);
}

// Round 7
// 70.156 us; speedup vs baseline: 1.9463x; 1.9463x over previous
//
#include <hip/hip_runtime.h>

#define EPS 1e-5f

typedef __attribute__((ext_vector_type(4))) float f32x4;
typedef __attribute__((ext_vector_type(8))) _Float16 f16x8;
typedef __attribute__((ext_vector_type(4))) _Float16 f16x4;

// ============ kernel 1: prep ∥ convxT/xh ∥ am->fp16 ============
// blocks [0,256): x -> XT (transposed fp16) + xh (row-major fp16)
// blocks [256,320): BN-fold weights, biases, offsets, task table (32-row tiles)
// blocks [320,832): am fp32 -> amh fp16 (rows/cols < l per graph)
__global__ __launch_bounds__(256) void prep_conv_kernel(
    const int* __restrict__ ld, const float* __restrict__ am,
    const float* __restrict__ Wl, const float* __restrict__ bl,
    const float* __restrict__ gl, const float* __restrict__ betal,
    const float* __restrict__ ml, const float* __restrict__ vl,
    const float* __restrict__ W1, const float* __restrict__ b1,
    const float* __restrict__ g1, const float* __restrict__ beta1,
    const float* __restrict__ m1, const float* __restrict__ v1,
    const float* __restrict__ W2, const float* __restrict__ b2,
    const float* __restrict__ g2, const float* __restrict__ beta2,
    const float* __restrict__ m2, const float* __restrict__ v2,
    int* __restrict__ offs, float* __restrict__ c1, float* __restrict__ cf,
    int* __restrict__ tg, int* __restrict__ tr, int n_tasks,
    _Float16* __restrict__ W1h, _Float16* __restrict__ Wch,
    _Float16* __restrict__ amh,
    const float* __restrict__ x, _Float16* __restrict__ XT,
    _Float16* __restrict__ xh, int M)
{
    __shared__ __align__(16) _Float16 Tt[128][80];
    int t = threadIdx.x;
    if (blockIdx.x < 256) {
        int m0 = blockIdx.x * 64;
        #pragma unroll
        for (int p = 0; p < 8; ++p) {
            int idx = t + p * 256;
            int m = idx >> 5;
            int f = (idx & 31) * 4;
            float4 v = *(const float4*)&x[(size_t)(m0 + m) * 128 + f];
            Tt[f + 0][m] = (_Float16)v.x; Tt[f + 1][m] = (_Float16)v.y;
            Tt[f + 2][m] = (_Float16)v.z; Tt[f + 3][m] = (_Float16)v.w;
            f16x4 h;
            h[0] = (_Float16)v.x; h[1] = (_Float16)v.y;
            h[2] = (_Float16)v.z; h[3] = (_Float16)v.w;
            *(f16x4*)&xh[(size_t)(m0 + m) * 128 + f] = h;
        }
        __syncthreads();
        #pragma unroll
        for (int p = 0; p < 4; ++p) {
            int idx = t + p * 256;
            int f = idx >> 3;
            int m8 = (idx & 7) * 8;
            uint4 v = *(const uint4*)&Tt[f][m8];
            *(uint4*)&XT[(size_t)f * M + m0 + m8] = v;
        }
    } else if (blockIdx.x < 320) {
        int b = blockIdx.x - 256;
        int gt = b * 256 + t;
        const int gsize = 64 * 256;
        if (b == 0) {
            if (t < 64) {
                int s = 0;
                for (int i = 0; i < t; ++i) s += ld[i];
                offs[t] = s;
            }
            if (t < 128) {
                float s1 = g1[t] * rsqrtf(v1[t] + EPS);
                c1[t] = (b1[t] - m1[t]) * s1 + beta1[t];
            }
            if (t < 256) {
                float s2 = g2[t] * rsqrtf(v2[t] + EPS);
                float sl = gl[t] * rsqrtf(vl[t] + EPS);
                cf[t] = (b2[t] - m2[t]) * s2 + beta2[t] + (bl[t] - ml[t]) * sl + betal[t];
            }
            // task table: 32-row tiles over the ragged rows
            for (int t2 = t; t2 < n_tasks; t2 += 256) {
                int rem = t2, gg = 0;
                while (true) {
                    int n = ld[gg] >> 5;
                    if (rem < n) break;
                    rem -= n; ++gg;
                }
                tg[t2] = gg;
                tr[t2] = rem << 5;
            }
        }
        for (int idx = gt; idx < 128 * 128; idx += gsize) {
            int n = idx >> 7;
            float s1 = g1[n] * rsqrtf(v1[n] + EPS);
            W1h[idx] = (_Float16)(W1[idx] * s1);
        }
        for (int idx = gt; idx < 256 * 256; idx += gsize) {
            int n = idx >> 8, k = idx & 255;
            float v;
            if (k < 128) {
                float s2 = g2[n] * rsqrtf(v2[n] + EPS);
                v = W2[n * 128 + k] * s2;
            } else {
                float sl = gl[n] * rsqrtf(vl[n] + EPS);
                v = Wl[n * 128 + (k - 128)] * sl;
            }
            Wch[idx] = (_Float16)v;
        }
    } else {
        // am -> fp16, 32-row tile per block (512 blocks)
        int t2 = blockIdx.x - 320;
        int rem = t2, gg = 0;
        while (true) {
            int n = ld[gg] >> 5;
            if (rem < n) break;
            rem -= n; ++gg;
        }
        int r0 = rem << 5;
        int l = ld[gg];
        const float* src = am + (size_t)gg * (512 * 512);
        _Float16* dst = amh + (size_t)gg * (512 * 512);
        int lq = l >> 2;                 // quads per row
        int tot = lq << 5;               // 32 rows
        for (int q = t; q < tot; q += 256) {
            int row = q / lq;
            int c4 = (q - row * lq) << 2;
            size_t o = (size_t)(r0 + row) * 512 + c4;
            float4 v = *(const float4*)&src[o];
            f16x4 h;
            h[0] = (_Float16)v.x; h[1] = (_Float16)v.y;
            h[2] = (_Float16)v.z; h[3] = (_Float16)v.w;
            *(f16x4*)&dst[o] = h;
        }
    }
}

// ============ kernel 2: fused agg1 + lin1 -> h2T (32-row tasks, 4 waves) ============
// wave (rt = w>>1, half = w&1): phase A computes 16 rows x 64 feats, operands
// direct from global (amh fp16). Exchange via LDS. Phase B: 64 out-feats.
__global__ __launch_bounds__(256) void fused1w_kernel(
    const _Float16* __restrict__ amh, const _Float16* __restrict__ XT,
    const int* __restrict__ ld, const int* __restrict__ offs,
    const int* __restrict__ tg, const int* __restrict__ tr,
    const _Float16* __restrict__ Wh, const float* __restrict__ bias,
    _Float16* __restrict__ outT, int M)
{
    int task = blockIdx.x;
    int g = tg[task];
    int l = ld[g];
    int off = offs[g];

    int tid = threadIdx.x;
    int lane = tid & 63;
    int w = tid >> 6;
    int l15 = lane & 15;
    int l4 = lane >> 4;
    int half = w & 1;
    int rt = w >> 1;
    int r0 = tr[task] + rt * 16;
    int fb = half * 64;
    int gm0 = off + r0;

    __shared__ __align__(16) _Float16 Hs[2][16][136];

    // ---- phase A ----
    f32x4 acc[4];
    #pragma unroll
    for (int i = 0; i < 4; ++i) acc[i] = (f32x4){0.f, 0.f, 0.f, 0.f};

    const _Float16* arow = amh + (size_t)g * (512 * 512) + (size_t)(r0 + l15) * 512 + l4 * 8;
    uint4 pa[4]; uint4 pb;
    #pragma unroll
    for (int i = 0; i < 4; ++i)
        pa[i] = *(const uint4*)&XT[(size_t)(fb + i * 16 + l15) * M + off + l4 * 8];
    pb = *(const uint4*)arow;

    int nk = l >> 5;
    for (int s = 0; s < nk; ++s) {
        uint4 ca[4] = {pa[0], pa[1], pa[2], pa[3]};
        uint4 cb = pb;
        if (s + 1 < nk) {
            int k0 = (s + 1) * 32;
            #pragma unroll
            for (int i = 0; i < 4; ++i)
                pa[i] = *(const uint4*)&XT[(size_t)(fb + i * 16 + l15) * M + off + k0 + l4 * 8];
            pb = *(const uint4*)(arow + k0);
        }
        f16x8 b = *(f16x8*)&cb;
        #pragma unroll
        for (int i = 0; i < 4; ++i) {
            f16x8 av = *(f16x8*)&ca[i];
            acc[i] = __builtin_amdgcn_mfma_f32_16x16x32_f16(av, b, acc[i], 0, 0, 0);
        }
    }
    // spill: lane holds row m = l15 (local), feat = fb + i*16 + l4*4 + r
    #pragma unroll
    for (int i = 0; i < 4; ++i) {
        f16x4 o;
        #pragma unroll
        for (int r = 0; r < 4; ++r) o[r] = (_Float16)acc[i][r];
        *(f16x4*)&Hs[rt][l15][fb + i * 16 + l4 * 4] = o;
    }
    __syncthreads();

    // ---- phase B: K=128, this wave computes out-feats [nb, nb+64) ----
    f32x4 acc2[4];
    #pragma unroll
    for (int j = 0; j < 4; ++j) acc2[j] = (f32x4){0.f, 0.f, 0.f, 0.f};
    int nb = half * 64;
    #pragma unroll
    for (int s = 0; s < 4; ++s) {
        int k0 = s * 32;
        f16x8 a = *(const f16x8*)&Hs[rt][l15][k0 + l4 * 8];
        #pragma unroll
        for (int j = 0; j < 4; ++j) {
            f16x8 b = *(const f16x8*)&Wh[(size_t)(nb + j * 16 + l15) * 128 + k0 + l4 * 8];
            acc2[j] = __builtin_amdgcn_mfma_f32_16x16x32_f16(a, b, acc2[j], 0, 0, 0);
        }
    }
    #pragma unroll
    for (int j = 0; j < 4; ++j) {
        int n = nb + j * 16 + l15;
        float bv = bias[n];
        f16x4 o;
        #pragma unroll
        for (int r = 0; r < 4; ++r) {
            float v = acc2[j][r] + bv;
            o[r] = (_Float16)(v > 0.f ? v : 0.f);
        }
        *(f16x4*)&outT[(size_t)n * M + gm0 + l4 * 4] = o;
    }
}

// ============ kernel 3: fused agg2 + final -> out fp32 (32-row tasks, 4 waves) ============
__global__ __launch_bounds__(256) void fused2w_kernel(
    const _Float16* __restrict__ amh, const _Float16* __restrict__ H2T,
    const int* __restrict__ ld, const int* __restrict__ offs,
    const int* __restrict__ tg, const int* __restrict__ tr,
    const _Float16* __restrict__ xh, const _Float16* __restrict__ Wch,
    const float* __restrict__ bias, float* __restrict__ out, int M)
{
    int task = blockIdx.x;
    int g = tg[task];
    int l = ld[g];
    int off = offs[g];

    int tid = threadIdx.x;
    int lane = tid & 63;
    int w = tid >> 6;
    int l15 = lane & 15;
    int l4 = lane >> 4;
    int half = w & 1;
    int rt = w >> 1;
    int r0 = tr[task] + rt * 16;
    int fb = half * 64;
    int gm0 = off + r0;

    __shared__ __align__(16) _Float16 Hs[2][16][136];

    // ---- phase A: agg2 from h2T ----
    f32x4 acc[4];
    #pragma unroll
    for (int i = 0; i < 4; ++i) acc[i] = (f32x4){0.f, 0.f, 0.f, 0.f};

    const _Float16* arow = amh + (size_t)g * (512 * 512) + (size_t)(r0 + l15) * 512 + l4 * 8;
    uint4 pa[4]; uint4 pb;
    #pragma unroll
    for (int i = 0; i < 4; ++i)
        pa[i] = *(const uint4*)&H2T[(size_t)(fb + i * 16 + l15) * M + off + l4 * 8];
    pb = *(const uint4*)arow;

    int nk = l >> 5;
    for (int s = 0; s < nk; ++s) {
        uint4 ca[4] = {pa[0], pa[1], pa[2], pa[3]};
        uint4 cb = pb;
        if (s + 1 < nk) {
            int k0 = (s + 1) * 32;
            #pragma unroll
            for (int i = 0; i < 4; ++i)
                pa[i] = *(const uint4*)&H2T[(size_t)(fb + i * 16 + l15) * M + off + k0 + l4 * 8];
            pb = *(const uint4*)(arow + k0);
        }
        f16x8 b = *(f16x8*)&cb;
        #pragma unroll
        for (int i = 0; i < 4; ++i) {
            f16x8 av = *(f16x8*)&ca[i];
            acc[i] = __builtin_amdgcn_mfma_f32_16x16x32_f16(av, b, acc[i], 0, 0, 0);
        }
    }
    #pragma unroll
    for (int i = 0; i < 4; ++i) {
        f16x4 o;
        #pragma unroll
        for (int r = 0; r < 4; ++r) o[r] = (_Float16)acc[i][r];
        *(f16x4*)&Hs[rt][l15][fb + i * 16 + l4 * 4] = o;
    }
    __syncthreads();

    // ---- phase B: K=256 ([h3 | x]), this wave computes out-feats [nb, nb+128) ----
    f32x4 acc2[8];
    #pragma unroll
    for (int j = 0; j < 8; ++j) acc2[j] = (f32x4){0.f, 0.f, 0.f, 0.f};
    int nb = half * 128;
    #pragma unroll
    for (int s = 0; s < 8; ++s) {
        int k0 = s * 32;
        f16x8 a;
        if (s < 4)
            a = *(const f16x8*)&Hs[rt][l15][k0 + l4 * 8];
        else
            a = *(const f16x8*)&xh[(size_t)(gm0 + l15) * 128 + (k0 - 128) + l4 * 8];
        #pragma unroll
        for (int j = 0; j < 8; ++j) {
            f16x8 b = *(const f16x8*)&Wch[(size_t)(nb + j * 16 + l15) * 256 + k0 + l4 * 8];
            acc2[j] = __builtin_amdgcn_mfma_f32_16x16x32_f16(a, b, acc2[j], 0, 0, 0);
        }
    }
    #pragma unroll
    for (int j = 0; j < 8; ++j) {
        int n = nb + j * 16 + l15;
        float bv = bias[n];
        #pragma unroll
        for (int r = 0; r < 4; ++r) {
            int m = gm0 + l4 * 4 + r;
            float v = acc2[j][r] + bv;
            out[(size_t)m * 256 + n] = v > 0.f ? v : 0.01f * v;
        }
    }
}

extern "C" void kernel_launch(void* const* d_in, const int* in_sizes, int n_in,
                              void* d_out, int out_size, void* d_ws, size_t ws_size,
                              hipStream_t stream) {
    const float* x     = (const float*)d_in[0];
    const int*   ld    = (const int*)d_in[1];
    const float* am    = (const float*)d_in[2];
    const float* Wl    = (const float*)d_in[3];
    const float* bl    = (const float*)d_in[4];
    const float* gl    = (const float*)d_in[5];
    const float* betal = (const float*)d_in[6];
    const float* ml    = (const float*)d_in[7];
    const float* vl    = (const float*)d_in[8];
    const float* W1    = (const float*)d_in[9];
    const float* b1    = (const float*)d_in[10];
    const float* g1    = (const float*)d_in[11];
    const float* beta1 = (const float*)d_in[12];
    const float* m1    = (const float*)d_in[13];
    const float* v1    = (const float*)d_in[14];
    const float* W2    = (const float*)d_in[15];
    const float* b2    = (const float*)d_in[16];
    const float* g2    = (const float*)d_in[17];
    const float* beta2 = (const float*)d_in[18];
    const float* m2    = (const float*)d_in[19];
    const float* v2    = (const float*)d_in[20];
    float* out = (float*)d_out;

    int M = in_sizes[0] / 128;   // 16384
    int n_tasks = M / 32;        // 512

    char* w = (char*)d_ws;
    int*   offs = (int*)(w);                    // 64 int
    float* c1   = (float*)(w + 512);            // 128 f
    float* cf   = (float*)(w + 1024);           // 256 f
    int*   tg   = (int*)(w + 2048);             // 512 int
    int*   tr   = (int*)(w + 6144);             // 512 int
    _Float16* W1h = (_Float16*)(w + 16384);     // 128*128
    _Float16* Wch = (_Float16*)(w + 49152);     // 256*256
    _Float16* amh = (_Float16*)(w + 180224);    // 64*512*512 fp16 = 33.5 MB
    _Float16* XT  = (_Float16*)(w + 180224 + (size_t)64 * 512 * 512 * 2);
    _Float16* xh  = XT + (size_t)M * 128;
    _Float16* h2T = xh + (size_t)M * 128;

    prep_conv_kernel<<<832, 256, 0, stream>>>(ld, am,
        Wl, bl, gl, betal, ml, vl,
        W1, b1, g1, beta1, m1, v1,
        W2, b2, g2, beta2, m2, v2,
        offs, c1, cf, tg, tr, n_tasks, W1h, Wch, amh, x, XT, xh, M);

    fused1w_kernel<<<n_tasks, 256, 0, stream>>>(amh, XT, ld, offs, tg, tr, W1h, c1, h2T, M);

    fused2w_kernel<<<n_tasks, 256, 0, stream>>>(amh, h2T, ld, offs, tg, tr, xh, Wch, cf, out, M);
}

// Round 8
// 59.734 us; speedup vs baseline: 2.2859x; 1.1745x over previous
//
#include <hip/hip_runtime.h>

#define EPS 1e-5f

typedef __attribute__((ext_vector_type(4))) float f32x4;
typedef __attribute__((ext_vector_type(8))) _Float16 f16x8;
typedef __attribute__((ext_vector_type(4))) _Float16 f16x4;

// fragment-ordered tiled index: row r (16-tiled), col k (32-tiled), K = row length.
// within a (16r x 32k) tile: [r&15][(k&31)>>3][k&7] -> lane(l15,l4) reads contiguous 16B.
__device__ __forceinline__ int tidx(int r, int k, int K) {
    return (r >> 4) * (K << 4) + ((k >> 5) << 9) + ((r & 15) << 5) + (((k & 31) >> 3) << 3) + (k & 7);
}

#define MFMA16(a, b, c) __builtin_amdgcn_mfma_f32_16x16x32_f16(a, b, c, 0, 0, 0)

// ============ kernel 1: prep ============
// [0,256):   x -> XTt (feat-major tiled) + xh_t (node-major tiled)
// [256,320): BN-fold weights into tiled W1t/Wct, biases, offsets, task tables
// [320,832): am fp32 -> amt fp16 (tiled, packed per graph at ta)
__global__ __launch_bounds__(256) void prep_conv_kernel(
    const int* __restrict__ ld, const float* __restrict__ am,
    const float* __restrict__ Wl, const float* __restrict__ bl,
    const float* __restrict__ gl, const float* __restrict__ betal,
    const float* __restrict__ ml, const float* __restrict__ vl,
    const float* __restrict__ W1, const float* __restrict__ b1,
    const float* __restrict__ g1, const float* __restrict__ beta1,
    const float* __restrict__ m1, const float* __restrict__ v1,
    const float* __restrict__ W2, const float* __restrict__ b2,
    const float* __restrict__ g2, const float* __restrict__ beta2,
    const float* __restrict__ m2, const float* __restrict__ v2,
    int* __restrict__ offs, float* __restrict__ c1, float* __restrict__ cf,
    int* __restrict__ tg, int* __restrict__ tr, int* __restrict__ ta, int n_tasks,
    _Float16* __restrict__ W1t, _Float16* __restrict__ Wct,
    _Float16* __restrict__ amt,
    const float* __restrict__ x, _Float16* __restrict__ XTt,
    _Float16* __restrict__ xh_t, int M)
{
    __shared__ __align__(16) _Float16 Tt[128][80];
    int t = threadIdx.x;
    if (blockIdx.x < 256) {
        int m0 = blockIdx.x * 64;
        // find graph for this 64-node block (nodes per graph are multiples of 64)
        int gg = 0, off = 0;
        while (m0 >= off + ld[gg]) { off += ld[gg]; ++gg; }
        int l = ld[gg];
        #pragma unroll
        for (int p = 0; p < 8; ++p) {
            int idx = t + p * 256;
            int m = idx >> 5;
            int f = (idx & 31) * 4;
            float4 v = *(const float4*)&x[(size_t)(m0 + m) * 128 + f];
            Tt[f + 0][m] = (_Float16)v.x; Tt[f + 1][m] = (_Float16)v.y;
            Tt[f + 2][m] = (_Float16)v.z; Tt[f + 3][m] = (_Float16)v.w;
            f16x4 h;
            h[0] = (_Float16)v.x; h[1] = (_Float16)v.y;
            h[2] = (_Float16)v.z; h[3] = (_Float16)v.w;
            *(f16x4*)&xh_t[tidx(m0 + m, f, 128)] = h;   // f%4==0 -> contiguous
        }
        __syncthreads();
        #pragma unroll
        for (int p = 0; p < 4; ++p) {
            int idx = t + p * 256;
            int f = idx >> 3;              // feat 0..127
            int m8 = (idx & 7) * 8;        // node 0..56 step 8
            int kl = m0 - off + m8;        // graph-local node
            uint4 v = *(const uint4*)&Tt[f][m8];
            *(uint4*)&XTt[off * 128 + tidx(f, kl, l)] = v;  // kl%8==0 -> contiguous 16B
        }
    } else if (blockIdx.x < 320) {
        int b = blockIdx.x - 256;
        int gt = b * 256 + t;
        const int gsize = 64 * 256;
        if (b == 0) {
            if (t < 64) {
                int s = 0;
                for (int i = 0; i < t; ++i) s += ld[i];
                offs[t] = s;
            }
            if (t < 128) {
                float s1 = g1[t] * rsqrtf(v1[t] + EPS);
                c1[t] = (b1[t] - m1[t]) * s1 + beta1[t];
            }
            if (t < 256) {
                float s2 = g2[t] * rsqrtf(v2[t] + EPS);
                float sl = gl[t] * rsqrtf(vl[t] + EPS);
                cf[t] = (b2[t] - m2[t]) * s2 + beta2[t] + (bl[t] - ml[t]) * sl + betal[t];
            }
            // task table (32-row tiles) + packed am base per task
            for (int t2 = t; t2 < n_tasks; t2 += 256) {
                int rem = t2, gg = 0, amo = 0;
                while (true) {
                    int n = ld[gg] >> 5;
                    if (rem < n) break;
                    rem -= n; amo += ld[gg] * ld[gg]; ++gg;
                }
                tg[t2] = gg;
                tr[t2] = rem << 5;
                ta[t2] = amo;
            }
        }
        for (int idx = gt; idx < 128 * 128; idx += gsize) {
            int n = idx >> 7, k = idx & 127;
            float s1 = g1[n] * rsqrtf(v1[n] + EPS);
            W1t[tidx(n, k, 128)] = (_Float16)(W1[idx] * s1);
        }
        for (int idx = gt; idx < 256 * 256; idx += gsize) {
            int n = idx >> 8, k = idx & 255;
            float v;
            if (k < 128) {
                float s2 = g2[n] * rsqrtf(v2[n] + EPS);
                v = W2[n * 128 + k] * s2;
            } else {
                float sl = gl[n] * rsqrtf(vl[n] + EPS);
                v = Wl[n * 128 + (k - 128)] * sl;
            }
            Wct[tidx(n, k, 256)] = (_Float16)v;
        }
    } else {
        // am fp32 -> amt fp16 tiled; one 32-row tile per block (512 blocks)
        int t2 = blockIdx.x - 320;
        int rem = t2, gg = 0, amo = 0;
        while (true) {
            int n = ld[gg] >> 5;
            if (rem < n) break;
            rem -= n; amo += ld[gg] * ld[gg]; ++gg;
        }
        int r0 = rem << 5;
        int l = ld[gg];
        const float* src = am + (size_t)gg * (512 * 512);
        _Float16* dst = amt + amo;
        int lq = l >> 2;                 // quads per row
        int tot = lq << 5;               // 32 rows
        for (int q = t; q < tot; q += 256) {
            int row = q / lq;
            int c4 = (q - row * lq) << 2;
            float4 v = *(const float4*)&src[(size_t)(r0 + row) * 512 + c4];
            f16x4 h;
            h[0] = (_Float16)v.x; h[1] = (_Float16)v.y;
            h[2] = (_Float16)v.z; h[3] = (_Float16)v.w;
            *(f16x4*)&dst[tidx(r0 + row, c4, l)] = h;   // c4%4==0 -> contiguous
        }
    }
}

// ============ kernel 2: fused agg1 + lin1 -> H2Tt ============
__global__ __launch_bounds__(256) void fused1w_kernel(
    const _Float16* __restrict__ amt, const _Float16* __restrict__ XTt,
    const int* __restrict__ ld, const int* __restrict__ offs,
    const int* __restrict__ tg, const int* __restrict__ tr, const int* __restrict__ ta,
    const _Float16* __restrict__ W1t, const float* __restrict__ bias,
    _Float16* __restrict__ H2Tt)
{
    // XCD-chunked swizzle (512 blocks, 8 XCDs -> 64 contiguous tasks per XCD)
    int task = ((blockIdx.x & 7) << 6) + (blockIdx.x >> 3);
    int g = tg[task];
    int l = ld[g];
    int off = offs[g];

    int tid = threadIdx.x;
    int lane = tid & 63;
    int w = tid >> 6;
    int l15 = lane & 15;
    int l4 = lane >> 4;
    int half = w & 1;
    int rt = w >> 1;
    int r0l = tr[task] + rt * 16;

    __shared__ __align__(16) _Float16 Hs[2][16][136];

    const int lane_off = (l15 << 5) + (l4 << 3);
    const int ts = l << 4;               // 16*l, stride of one row-tile
    const _Float16* ap0 = XTt + off * 128 + (half * 4) * ts + lane_off;
    const _Float16* ap1 = ap0 + ts;
    const _Float16* ap2 = ap1 + ts;
    const _Float16* ap3 = ap2 + ts;
    const _Float16* bp  = amt + ta[task] + (r0l >> 4) * ts + lane_off;

    f32x4 a0 = {0.f,0.f,0.f,0.f}, a1 = a0, a2 = a0, a3 = a0;

    int nk = l >> 5;                     // 4 or 12 (even)
    uint4 p0 = *(const uint4*)ap0, p1 = *(const uint4*)ap1;
    uint4 p2 = *(const uint4*)ap2, p3 = *(const uint4*)ap3;
    uint4 pb = *(const uint4*)bp;
    uint4 q0 = *(const uint4*)(ap0 + 512), q1 = *(const uint4*)(ap1 + 512);
    uint4 q2 = *(const uint4*)(ap2 + 512), q3 = *(const uint4*)(ap3 + 512);
    uint4 qb = *(const uint4*)(bp + 512);

    for (int s = 0; s < nk; s += 2) {
        uint4 c0 = p0, c1 = p1, c2 = p2, c3 = p3, cb = pb;
        if (s + 2 < nk) {
            int o = (s + 2) << 9;
            p0 = *(const uint4*)(ap0 + o); p1 = *(const uint4*)(ap1 + o);
            p2 = *(const uint4*)(ap2 + o); p3 = *(const uint4*)(ap3 + o);
            pb = *(const uint4*)(bp + o);
        }
        {
            f16x8 b = *(f16x8*)&cb;
            a0 = MFMA16(*(f16x8*)&c0, b, a0);
            a1 = MFMA16(*(f16x8*)&c1, b, a1);
            a2 = MFMA16(*(f16x8*)&c2, b, a2);
            a3 = MFMA16(*(f16x8*)&c3, b, a3);
        }
        uint4 d0 = q0, d1 = q1, d2 = q2, d3 = q3, db = qb;
        if (s + 3 < nk) {
            int o = (s + 3) << 9;
            q0 = *(const uint4*)(ap0 + o); q1 = *(const uint4*)(ap1 + o);
            q2 = *(const uint4*)(ap2 + o); q3 = *(const uint4*)(ap3 + o);
            qb = *(const uint4*)(bp + o);
        }
        {
            f16x8 b = *(f16x8*)&db;
            a0 = MFMA16(*(f16x8*)&d0, b, a0);
            a1 = MFMA16(*(f16x8*)&d1, b, a1);
            a2 = MFMA16(*(f16x8*)&d2, b, a2);
            a3 = MFMA16(*(f16x8*)&d3, b, a3);
        }
    }
    // spill h1: lane row = l15, feat = half*64 + i*16 + l4*4 + r
    int fb = half * 64;
    {
        f32x4 aa[4] = {a0, a1, a2, a3};
        #pragma unroll
        for (int i = 0; i < 4; ++i) {
            f16x4 o;
            #pragma unroll
            for (int r = 0; r < 4; ++r) o[r] = (_Float16)aa[i][r];
            *(f16x4*)&Hs[rt][l15][fb + i * 16 + l4 * 4] = o;
        }
    }
    __syncthreads();

    // phase B: K=128, out-feats [half*64, half*64+64)
    f32x4 e0 = {0.f,0.f,0.f,0.f}, e1 = e0, e2 = e0, e3 = e0;
    #pragma unroll
    for (int s = 0; s < 4; ++s) {
        f16x8 a = *(const f16x8*)&Hs[rt][l15][(s << 5) + (l4 << 3)];
        const _Float16* wp = W1t + (half * 4) * 2048 + (s << 9) + lane_off;
        e0 = MFMA16(a, *(const f16x8*)(wp),        e0);
        e1 = MFMA16(a, *(const f16x8*)(wp + 2048), e1);
        e2 = MFMA16(a, *(const f16x8*)(wp + 4096), e2);
        e3 = MFMA16(a, *(const f16x8*)(wp + 6144), e3);
    }
    int hb = off * 128;
    int kkb = r0l + (l4 << 2);
    f32x4 ee[4] = {e0, e1, e2, e3};
    #pragma unroll
    for (int j = 0; j < 4; ++j) {
        int n = half * 64 + j * 16 + l15;
        float bv = bias[n];
        f16x4 o;
        #pragma unroll
        for (int r = 0; r < 4; ++r) {
            float v = ee[j][r] + bv;
            o[r] = (_Float16)(v > 0.f ? v : 0.f);
        }
        *(f16x4*)&H2Tt[hb + tidx(n, kkb, l)] = o;
    }
}

// ============ kernel 3: fused agg2 + final -> out fp32 ============
__global__ __launch_bounds__(256) void fused2w_kernel(
    const _Float16* __restrict__ amt, const _Float16* __restrict__ H2Tt,
    const int* __restrict__ ld, const int* __restrict__ offs,
    const int* __restrict__ tg, const int* __restrict__ tr, const int* __restrict__ ta,
    const _Float16* __restrict__ xh_t, const _Float16* __restrict__ Wct,
    const float* __restrict__ bias, float* __restrict__ out)
{
    int task = ((blockIdx.x & 7) << 6) + (blockIdx.x >> 3);
    int g = tg[task];
    int l = ld[g];
    int off = offs[g];

    int tid = threadIdx.x;
    int lane = tid & 63;
    int w = tid >> 6;
    int l15 = lane & 15;
    int l4 = lane >> 4;
    int half = w & 1;
    int rt = w >> 1;
    int r0l = tr[task] + rt * 16;
    int gm0 = off + r0l;

    __shared__ __align__(16) _Float16 Hs[2][16][136];

    const int lane_off = (l15 << 5) + (l4 << 3);
    const int ts = l << 4;
    const _Float16* ap0 = H2Tt + off * 128 + (half * 4) * ts + lane_off;
    const _Float16* ap1 = ap0 + ts;
    const _Float16* ap2 = ap1 + ts;
    const _Float16* ap3 = ap2 + ts;
    const _Float16* bp  = amt + ta[task] + (r0l >> 4) * ts + lane_off;

    f32x4 a0 = {0.f,0.f,0.f,0.f}, a1 = a0, a2 = a0, a3 = a0;

    int nk = l >> 5;
    uint4 p0 = *(const uint4*)ap0, p1 = *(const uint4*)ap1;
    uint4 p2 = *(const uint4*)ap2, p3 = *(const uint4*)ap3;
    uint4 pb = *(const uint4*)bp;
    uint4 q0 = *(const uint4*)(ap0 + 512), q1 = *(const uint4*)(ap1 + 512);
    uint4 q2 = *(const uint4*)(ap2 + 512), q3 = *(const uint4*)(ap3 + 512);
    uint4 qb = *(const uint4*)(bp + 512);

    for (int s = 0; s < nk; s += 2) {
        uint4 c0 = p0, c1 = p1, c2 = p2, c3 = p3, cb = pb;
        if (s + 2 < nk) {
            int o = (s + 2) << 9;
            p0 = *(const uint4*)(ap0 + o); p1 = *(const uint4*)(ap1 + o);
            p2 = *(const uint4*)(ap2 + o); p3 = *(const uint4*)(ap3 + o);
            pb = *(const uint4*)(bp + o);
        }
        {
            f16x8 b = *(f16x8*)&cb;
            a0 = MFMA16(*(f16x8*)&c0, b, a0);
            a1 = MFMA16(*(f16x8*)&c1, b, a1);
            a2 = MFMA16(*(f16x8*)&c2, b, a2);
            a3 = MFMA16(*(f16x8*)&c3, b, a3);
        }
        uint4 d0 = q0, d1 = q1, d2 = q2, d3 = q3, db = qb;
        if (s + 3 < nk) {
            int o = (s + 3) << 9;
            q0 = *(const uint4*)(ap0 + o); q1 = *(const uint4*)(ap1 + o);
            q2 = *(const uint4*)(ap2 + o); q3 = *(const uint4*)(ap3 + o);
            qb = *(const uint4*)(bp + o);
        }
        {
            f16x8 b = *(f16x8*)&db;
            a0 = MFMA16(*(f16x8*)&d0, b, a0);
            a1 = MFMA16(*(f16x8*)&d1, b, a1);
            a2 = MFMA16(*(f16x8*)&d2, b, a2);
            a3 = MFMA16(*(f16x8*)&d3, b, a3);
        }
    }
    int fb = half * 64;
    {
        f32x4 aa[4] = {a0, a1, a2, a3};
        #pragma unroll
        for (int i = 0; i < 4; ++i) {
            f16x4 o;
            #pragma unroll
            for (int r = 0; r < 4; ++r) o[r] = (_Float16)aa[i][r];
            *(f16x4*)&Hs[rt][l15][fb + i * 16 + l4 * 4] = o;
        }
    }
    __syncthreads();

    // phase B: K=256 ([h3 | x]), out-feats [half*128, half*128+128)
    f32x4 e[8];
    #pragma unroll
    for (int j = 0; j < 8; ++j) e[j] = (f32x4){0.f, 0.f, 0.f, 0.f};
    const _Float16* wbase = Wct + (half * 8) * 4096 + lane_off;
    #pragma unroll
    for (int s = 0; s < 4; ++s) {
        f16x8 a = *(const f16x8*)&Hs[rt][l15][(s << 5) + (l4 << 3)];
        #pragma unroll
        for (int j = 0; j < 8; ++j) {
            f16x8 b = *(const f16x8*)(wbase + j * 4096 + (s << 9));
            e[j] = MFMA16(a, b, e[j]);
        }
    }
    const _Float16* xp = xh_t + (gm0 >> 4) * 2048 + lane_off;
    #pragma unroll
    for (int s = 0; s < 4; ++s) {
        f16x8 a = *(const f16x8*)(xp + (s << 9));
        #pragma unroll
        for (int j = 0; j < 8; ++j) {
            f16x8 b = *(const f16x8*)(wbase + j * 4096 + ((s + 4) << 9));
            e[j] = MFMA16(a, b, e[j]);
        }
    }
    #pragma unroll
    for (int j = 0; j < 8; ++j) {
        int n = half * 128 + j * 16 + l15;
        float bv = bias[n];
        #pragma unroll
        for (int r = 0; r < 4; ++r) {
            int m = gm0 + (l4 << 2) + r;
            float v = e[j][r] + bv;
            out[(size_t)m * 256 + n] = v > 0.f ? v : 0.01f * v;
        }
    }
}

extern "C" void kernel_launch(void* const* d_in, const int* in_sizes, int n_in,
                              void* d_out, int out_size, void* d_ws, size_t ws_size,
                              hipStream_t stream) {
    const float* x     = (const float*)d_in[0];
    const int*   ld    = (const int*)d_in[1];
    const float* am    = (const float*)d_in[2];
    const float* Wl    = (const float*)d_in[3];
    const float* bl    = (const float*)d_in[4];
    const float* gl    = (const float*)d_in[5];
    const float* betal = (const float*)d_in[6];
    const float* ml    = (const float*)d_in[7];
    const float* vl    = (const float*)d_in[8];
    const float* W1    = (const float*)d_in[9];
    const float* b1    = (const float*)d_in[10];
    const float* g1    = (const float*)d_in[11];
    const float* beta1 = (const float*)d_in[12];
    const float* m1    = (const float*)d_in[13];
    const float* v1    = (const float*)d_in[14];
    const float* W2    = (const float*)d_in[15];
    const float* b2    = (const float*)d_in[16];
    const float* g2    = (const float*)d_in[17];
    const float* beta2 = (const float*)d_in[18];
    const float* m2    = (const float*)d_in[19];
    const float* v2    = (const float*)d_in[20];
    float* out = (float*)d_out;

    int M = in_sizes[0] / 128;   // 16384
    int n_tasks = M / 32;        // 512

    char* w = (char*)d_ws;
    int*   offs = (int*)(w);                    // 64 int
    float* c1   = (float*)(w + 512);            // 128 f
    float* cf   = (float*)(w + 1024);           // 256 f
    int*   tg   = (int*)(w + 2048);             // 512 int
    int*   tr   = (int*)(w + 4096);             // 512 int
    int*   ta   = (int*)(w + 6144);             // 512 int
    _Float16* W1t = (_Float16*)(w + 16384);     // 128*128 = 32 KB
    _Float16* Wct = (_Float16*)(w + 49152);     // 256*256 = 128 KB
    _Float16* amt = (_Float16*)(w + 180224);    // sum(l^2) = 5.24M elems = 10.5 MB
    _Float16* XTt = (_Float16*)(w + 180224 + (size_t)10485760);
    _Float16* xh_t = XTt + (size_t)M * 128;
    _Float16* H2Tt = xh_t + (size_t)M * 128;

    prep_conv_kernel<<<832, 256, 0, stream>>>(ld, am,
        Wl, bl, gl, betal, ml, vl,
        W1, b1, g1, beta1, m1, v1,
        W2, b2, g2, beta2, m2, v2,
        offs, c1, cf, tg, tr, ta, n_tasks, W1t, Wct, amt, x, XTt, xh_t, M);

    fused1w_kernel<<<n_tasks, 256, 0, stream>>>(amt, XTt, ld, offs, tg, tr, ta, W1t, c1, H2Tt);

    fused2w_kernel<<<n_tasks, 256, 0, stream>>>(amt, H2Tt, ld, offs, tg, tr, ta, xh_t, Wct, cf, out);
}